// Round 13
// baseline (143.169 us; speedup 1.0000x reference)
//
#include <hip/hip_runtime.h>
#include <math.h>

#define NN   8192
#define NPHI 32
#define ROWS 2
#define TPB  256   // 4 waves of 64

typedef int iv4 __attribute__((ext_vector_type(4)));

// R12 + CROSS-ITERATION PREFETCH: ping-pong chunk-pairs so adjacency loads
// for chunks k+2,k+3 are in flight while chunks k,k+1 are consumed — the
// consume-side wait is vmcnt(4), never vmcnt(0); no per-iteration pipeline
// drain. VGPR: 2 pairs x 2 chunks x ROWS int4 = 32 load regs, total ~57 < 64
// cap of __launch_bounds__(256,8) -> 32 waves/CU retained.
__launch_bounds__(TPB, 8)
__global__ void maxdist_kernel(const float* __restrict__ prev,
                               const float* __restrict__ nodes,
                               const int* __restrict__ adj,
                               const float* __restrict__ W_phi,
                               const float* __restrict__ W_theta,
                               float* __restrict__ out) {
    const int tid  = threadIdx.x;
    const int lane = tid & 63;
    const int wave = tid >> 6;
    const int i0   = blockIdx.x * ROWS;

    const float w0 = W_theta[0], w1 = W_theta[1], w2 = W_theta[2];

    float a[ROWS], b[ROWS], c[ROWS], m[ROWS];
#pragma unroll
    for (int r = 0; r < ROWS; ++r) {
        const float yi0 = nodes[3 * (i0 + r) + 0] * w0;
        const float yi1 = nodes[3 * (i0 + r) + 1] * w1;
        const float yi2 = nodes[3 * (i0 + r) + 2] * w2;
        a[r] = -2.0f * yi0;
        b[r] = -2.0f * yi1;
        c[r] = -2.0f * yi2;
        m[r] = -INFINITY;   // running max of (sq_j - 2*dot); s_i added at the end
    }

    const int woff = wave * 256 + lane * 4;   // lane's j-offset inside a 1KB chunk

    // load one chunk-pair (chunks cb, cb+1): 4 int4 adjacency loads
    auto loadPair = [&](iv4 av[2][ROWS], int kpair) {
        const int j00 = kpair * 1024 + woff;
#pragma unroll
        for (int r = 0; r < ROWS; ++r)
            av[0][r] = *(const iv4*)(adj + (size_t)(i0 + r) * NN + j00);
#pragma unroll
        for (int r = 0; r < ROWS; ++r)
            av[1][r] = *(const iv4*)(adj + (size_t)(i0 + r) * NN + j00 + 1024);
    };

    // consume one chunk: y computed on the fly from 12 contiguous floats
    auto consume = [&](const iv4* av, int jbase) {
        const float4* nb = (const float4*)(nodes + 3 * jbase);
        const float4 q0 = nb[0], q1 = nb[1], q2 = nb[2];
        const float nf[12] = {q0.x, q0.y, q0.z, q0.w,
                              q1.x, q1.y, q1.z, q1.w,
                              q2.x, q2.y, q2.z, q2.w};
#pragma unroll
        for (int t = 0; t < 4; ++t) {
            const float y0 = nf[3 * t + 0] * w0;
            const float y1 = nf[3 * t + 1] * w1;
            const float y2 = nf[3 * t + 2] * w2;
            const float sq = fmaf(y0, y0, fmaf(y1, y1, y2 * y2));
#pragma unroll
            for (int r = 0; r < ROWS; ++r) {
                float d2 = fmaf(a[r], y0, fmaf(b[r], y1, fmaf(c[r], y2, sq)));
                d2 = (av[r][t] > 0) ? d2 : -INFINITY;
                m[r] = fmaxf(m[r], d2);
            }
        }
    };

    auto consumePair = [&](const iv4 av[2][ROWS], int kpair) {
        consume(av[0], kpair * 1024 + woff);
        consume(av[1], kpair * 1024 + woff + 1024);
    };

    // 8 chunks = 4 pairs; ping-pong A/B so 4 loads are always in flight
    iv4 avA[2][ROWS], avB[2][ROWS];
    loadPair(avA, 0);                       // chunks 0,1
    for (int k = 0; k < 8; k += 4) {
        loadPair(avB, k + 2);               // chunks k+2,k+3 in flight
        consumePair(avA, k);                //   while consuming k,k+1
        if (k + 4 < 8) loadPair(avA, k + 4);
        consumePair(avB, k + 2);
    }

    // wave-level max reduce
#pragma unroll
    for (int r = 0; r < ROWS; ++r) {
        float v = m[r];
#pragma unroll
        for (int off = 32; off > 0; off >>= 1)
            v = fmaxf(v, __shfl_xor(v, off, 64));
        m[r] = v;
    }

    __shared__ float red[4][ROWS];
    if (lane == 0) {
#pragma unroll
        for (int r = 0; r < ROWS; ++r) red[wave][r] = m[r];
    }

    float wp = (lane < NPHI) ? W_phi[lane] : 0.0f;
#pragma unroll
    for (int off = 32; off > 0; off >>= 1) wp += __shfl_xor(wp, off, 64);
    const float wmean = wp / (float)NPHI;

    __syncthreads();

    if (tid < ROWS) {
        const int r = tid;
        const float d2max = fmaxf(fmaxf(red[0][r], red[1][r]),
                                  fmaxf(red[2][r], red[3][r]));
        const int i = i0 + r;
        const float yi0 = nodes[3 * i + 0] * w0;
        const float yi1 = nodes[3 * i + 1] * w1;
        const float yi2 = nodes[3 * i + 2] * w2;
        const float si  = fmaf(yi0, yi0, fmaf(yi1, yi1, yi2 * yi2));
        float d2 = si + d2max;           // -inf if no neighbor
        d2 = fmaxf(d2, 0.0f);
        const float md = sqrtf(d2);
        out[i] = (prev[i] + md * wmean) * 0.5f;
    }
}

extern "C" void kernel_launch(void* const* d_in, const int* in_sizes, int n_in,
                              void* d_out, int out_size, void* d_ws, size_t ws_size,
                              hipStream_t stream) {
    const float* prev    = (const float*)d_in[0];
    const float* nodes   = (const float*)d_in[1];
    const int*   adj     = (const int*)d_in[2];
    const float* W_phi   = (const float*)d_in[3];
    const float* W_theta = (const float*)d_in[4];
    float* out = (float*)d_out;

    maxdist_kernel<<<NN / ROWS, TPB, 0, stream>>>(prev, nodes, adj, W_phi, W_theta, out);
}

// Round 14
// 45.352 us; speedup vs baseline: 3.1569x; 3.1569x over previous
//
#include <hip/hip_runtime.h>
#include <math.h>

#define NN   8192
#define NPHI 32
#define ROWS 2
#define TPB  256   // 4 waves of 64

typedef int iv4 __attribute__((ext_vector_type(4)));

// FINAL (R12 config): single fused kernel, no prep, no workspace.
// Each lane owns 4 consecutive j's; its y-inputs nodes[3*4l .. 3*4l+11] are
// one contiguous aligned 48 B run -> 3 float4 L1/L2-hit loads, y computed on
// the fly. Adjacency: 8 int4 loads in flight per wave (2 chunks x ROWS=2),
// 32 waves/CU via __launch_bounds__(256,8), 4096 blocks = 16/CU.
// Measured: 45.6 us ~= 93% of the 6.3 TB/s achievable read ceiling on the
// mandatory 256 MB adjacency stream. (R13's deeper ping-pong spilled to
// scratch -- VGPR_Count dropped to 32, 143 us -- reverted.)
__launch_bounds__(TPB, 8)
__global__ void maxdist_kernel(const float* __restrict__ prev,
                               const float* __restrict__ nodes,
                               const int* __restrict__ adj,
                               const float* __restrict__ W_phi,
                               const float* __restrict__ W_theta,
                               float* __restrict__ out) {
    const int tid  = threadIdx.x;
    const int lane = tid & 63;
    const int wave = tid >> 6;
    const int i0   = blockIdx.x * ROWS;

    const float w0 = W_theta[0], w1 = W_theta[1], w2 = W_theta[2];

    // per-row constants from nodes directly: a = -2*y_i
    float a[ROWS], b[ROWS], c[ROWS], m[ROWS];
#pragma unroll
    for (int r = 0; r < ROWS; ++r) {
        const float yi0 = nodes[3 * (i0 + r) + 0] * w0;
        const float yi1 = nodes[3 * (i0 + r) + 1] * w1;
        const float yi2 = nodes[3 * (i0 + r) + 2] * w2;
        a[r] = -2.0f * yi0;
        b[r] = -2.0f * yi1;
        c[r] = -2.0f * yi2;
        m[r] = -INFINITY;   // running max of (sq_j - 2*dot); s_i added at the end
    }

    const int woff = wave * 256 + lane * 4;   // lane's j-offset inside a 1KB chunk

    // consume one chunk: y computed on the fly from 12 contiguous floats
    auto consume = [&](const iv4* av, int jbase) {
        const float4* nb = (const float4*)(nodes + 3 * jbase);
        const float4 q0 = nb[0], q1 = nb[1], q2 = nb[2];
        const float nf[12] = {q0.x, q0.y, q0.z, q0.w,
                              q1.x, q1.y, q1.z, q1.w,
                              q2.x, q2.y, q2.z, q2.w};
#pragma unroll
        for (int t = 0; t < 4; ++t) {
            const float y0 = nf[3 * t + 0] * w0;
            const float y1 = nf[3 * t + 1] * w1;
            const float y2 = nf[3 * t + 2] * w2;
            const float sq = fmaf(y0, y0, fmaf(y1, y1, y2 * y2));
#pragma unroll
            for (int r = 0; r < ROWS; ++r) {
                float d2 = fmaf(a[r], y0, fmaf(b[r], y1, fmaf(c[r], y2, sq)));
                d2 = (av[r][t] > 0) ? d2 : -INFINITY;
                m[r] = fmaxf(m[r], d2);
            }
        }
    };

    // two 1KB chunks per iteration; all 8 adjacency loads issued up front
    for (int k = 0; k < NN / 1024; k += 2) {
        const int j00 = k * 1024 + woff;
        const int j01 = j00 + 1024;

        iv4 av0[ROWS], av1[ROWS];
#pragma unroll
        for (int r = 0; r < ROWS; ++r)
            av0[r] = *(const iv4*)(adj + (size_t)(i0 + r) * NN + j00);
#pragma unroll
        for (int r = 0; r < ROWS; ++r)
            av1[r] = *(const iv4*)(adj + (size_t)(i0 + r) * NN + j01);

        consume(av0, j00);
        consume(av1, j01);
    }

    // wave-level max reduce
#pragma unroll
    for (int r = 0; r < ROWS; ++r) {
        float v = m[r];
#pragma unroll
        for (int off = 32; off > 0; off >>= 1)
            v = fmaxf(v, __shfl_xor(v, off, 64));
        m[r] = v;
    }

    __shared__ float red[4][ROWS];
    if (lane == 0) {
#pragma unroll
        for (int r = 0; r < ROWS; ++r) red[wave][r] = m[r];
    }

    float wp = (lane < NPHI) ? W_phi[lane] : 0.0f;
#pragma unroll
    for (int off = 32; off > 0; off >>= 1) wp += __shfl_xor(wp, off, 64);
    const float wmean = wp / (float)NPHI;

    __syncthreads();

    if (tid < ROWS) {
        const int r = tid;
        const float d2max = fmaxf(fmaxf(red[0][r], red[1][r]),
                                  fmaxf(red[2][r], red[3][r]));
        const int i = i0 + r;
        const float yi0 = nodes[3 * i + 0] * w0;
        const float yi1 = nodes[3 * i + 1] * w1;
        const float yi2 = nodes[3 * i + 2] * w2;
        const float si  = fmaf(yi0, yi0, fmaf(yi1, yi1, yi2 * yi2));
        float d2 = si + d2max;           // -inf if no neighbor
        d2 = fmaxf(d2, 0.0f);
        const float md = sqrtf(d2);
        out[i] = (prev[i] + md * wmean) * 0.5f;
    }
}

extern "C" void kernel_launch(void* const* d_in, const int* in_sizes, int n_in,
                              void* d_out, int out_size, void* d_ws, size_t ws_size,
                              hipStream_t stream) {
    const float* prev    = (const float*)d_in[0];
    const float* nodes   = (const float*)d_in[1];
    const int*   adj     = (const int*)d_in[2];
    const float* W_phi   = (const float*)d_in[3];
    const float* W_theta = (const float*)d_in[4];
    float* out = (float*)d_out;

    maxdist_kernel<<<NN / ROWS, TPB, 0, stream>>>(prev, nodes, adj, W_phi, W_theta, out);
}